// Round 1
// baseline (224.909 us; speedup 1.0000x reference)
//
#include <hip/hip_runtime.h>
#include <hip/hip_bf16.h>

#define NBOX_MAX 2048
#define CAP 8
#define EPSF 1e-8f
#define NMS_THR 0.7f
#define TOPN 1000

// ---------------------------------------------------------------------------
// Rotated-rect intersection area, faithful fp32 port of the reference's
// Sutherland-Hodgman clip (crossing-point-before-current emission order,
// denom clamped to +EPS, CAP=8 truncation, shoelace with abs).
// ---------------------------------------------------------------------------
__device__ __forceinline__ float rect_inter_area(
    float xc1, float yc1, float w1, float h1, float t1,
    float xc2, float yc2, float w2, float h2, float t2)
{
    float px[CAP], py[CAP];
    {
        float c = cosf(t1), s = sinf(t1);
        float lx0 = -0.5f * w1, lx1 = 0.5f * w1;
        float ly0 = -0.5f * h1, ly1 = 0.5f * h1;
        px[0] = xc1 + lx0 * c - ly0 * s;  py[0] = yc1 + lx0 * s + ly0 * c;
        px[1] = xc1 + lx1 * c - ly0 * s;  py[1] = yc1 + lx1 * s + ly0 * c;
        px[2] = xc1 + lx1 * c - ly1 * s;  py[2] = yc1 + lx1 * s + ly1 * c;
        px[3] = xc1 + lx0 * c - ly1 * s;  py[3] = yc1 + lx0 * s + ly1 * c;
    }
    float qx[4], qy[4];
    {
        float c = cosf(t2), s = sinf(t2);
        float lx0 = -0.5f * w2, lx1 = 0.5f * w2;
        float ly0 = -0.5f * h2, ly1 = 0.5f * h2;
        qx[0] = xc2 + lx0 * c - ly0 * s;  qy[0] = yc2 + lx0 * s + ly0 * c;
        qx[1] = xc2 + lx1 * c - ly0 * s;  qy[1] = yc2 + lx1 * s + ly0 * c;
        qx[2] = xc2 + lx1 * c - ly1 * s;  qy[2] = yc2 + lx1 * s + ly1 * c;
        qx[3] = xc2 + lx0 * c - ly1 * s;  qy[3] = yc2 + lx0 * s + ly1 * c;
    }

    int n = 4;
    for (int e = 0; e < 4; ++e) {
        float p0x = qx[e], p0y = qy[e];
        int e1 = (e + 1) & 3;
        float ex = qx[e1] - p0x, ey = qy[e1] - p0y;

        float d[CAP];
        for (int k = 0; k < n; ++k)
            d[k] = ex * (py[k] - p0y) - ey * (px[k] - p0x);

        float nx[CAP], ny[CAP];
        int m = 0;
        for (int k = 0; k < n; ++k) {
            int kp = (k == 0) ? (n - 1) : (k - 1);
            float dc = d[k], dp = d[kp];
            bool cin = (dc >= 0.0f), pin = (dp >= 0.0f);
            if (cin != pin) {
                float den = dp - dc;
                if (fabsf(den) < EPSF) den = EPSF;
                float t = dp / den;
                if (m < CAP) {
                    nx[m] = px[kp] + t * (px[k] - px[kp]);
                    ny[m] = py[kp] + t * (py[k] - py[kp]);
                }
                ++m;
            }
            if (cin) {
                if (m < CAP) { nx[m] = px[k]; ny[m] = py[k]; }
                ++m;
            }
        }
        n = (m < CAP) ? m : CAP;
        for (int k = 0; k < n; ++k) { px[k] = nx[k]; py[k] = ny[k]; }
        if (n == 0) break;
    }

    if (n < 3) return 0.0f;
    float s = 0.0f;
    for (int k = 0; k < n; ++k) {
        int kn = (k + 1 == n) ? 0 : (k + 1);
        s += px[k] * py[kn] - py[k] * px[kn];
    }
    return 0.5f * fabsf(s);
}

// ---------------------------------------------------------------------------
// Kernel A: for each pair (i, j), j > i, set bit j in row i's suppression
// mask when iou >= 0.7. Conservative early rejects (bounding circle, area
// ratio) prune ~97% of pairs before the clip.
// ---------------------------------------------------------------------------
__global__ __launch_bounds__(256)
void iou_mask_kernel(const float* __restrict__ boxes,
                     unsigned long long* __restrict__ mask,
                     int n, int words)
{
    int i = blockIdx.y;
    int j = blockIdx.x * blockDim.x + threadIdx.x;
    if (j >= n || j <= i) return;

    const float* bi = boxes + (size_t)i * 5;
    const float* bj = boxes + (size_t)j * 5;
    float xi = bi[0], yi = bi[1], wi = bi[2], hi = bi[3], ti = bi[4];
    float xj = bj[0], yj = bj[1], wj = bj[2], hj = bj[3], tj = bj[4];

    // Bounding-circle reject: disjoint => inter exactly 0 in the reference.
    float dx = xi - xj, dy = yi - yj;
    float ri = 0.5f * sqrtf(wi * wi + hi * hi);
    float rj = 0.5f * sqrtf(wj * wj + hj * hj);
    float rr = ri + rj + 1e-3f;
    if (dx * dx + dy * dy > rr * rr) return;

    // Area-ratio reject: max possible iou = amin/amax (margin for fp noise).
    float a1 = wi * hi, a2 = wj * hj;
    float amin = fminf(a1, a2), amax = fmaxf(a1, a2);
    if (amin < 0.699f * amax) return;

    float inter = rect_inter_area(xi, yi, wi, hi, ti, xj, yj, wj, hj, tj);
    float iou = inter / (a1 + a2 - inter + EPSF);
    if (iou >= NMS_THR)
        atomicOr(&mask[(size_t)i * words + (j >> 6)], 1ULL << (j & 63));
}

// ---------------------------------------------------------------------------
// Kernel B: sequential greedy NMS on one wave. Lanes 0..31 own one 64-bit
// word of the running suppressed mask. 16-deep fully-unrolled register ring
// prefetches row i+16 while consuming row i (static indices -> registers).
// ---------------------------------------------------------------------------
__global__ __launch_bounds__(64)
void greedy_kernel(const unsigned long long* __restrict__ mask,
                   int* __restrict__ keep, int n, int words)
{
    const int lane = threadIdx.x;
    unsigned long long sup = 0ULL;
    unsigned long long buf[16];

#pragma unroll
    for (int k = 0; k < 16; ++k)
        buf[k] = (lane < words && k < n) ? mask[(size_t)k * words + lane] : 0ULL;

    int cnt = 0;
    for (int base = 0; base < n; base += 16) {
        if (cnt >= TOPN) break;
#pragma unroll
        for (int k = 0; k < 16; ++k) {
            int i = base + k;
            if (i < n) {
                unsigned long long supw = __shfl(sup, i >> 6);
                bool suppressed = (supw >> (i & 63)) & 1ULL;
                if (!suppressed && cnt < TOPN) {
                    if (lane == 0) keep[cnt] = i;
                    ++cnt;
                    sup |= buf[k];
                }
            }
            int nf = base + 16 + k;
            buf[k] = (lane < words && nf < n) ? mask[(size_t)nf * words + lane]
                                              : 0ULL;
        }
    }
}

extern "C" void kernel_launch(void* const* d_in, const int* in_sizes, int n_in,
                              void* d_out, int out_size, void* d_ws, size_t ws_size,
                              hipStream_t stream) {
    const float* boxes = (const float*)d_in[0];
    int n = in_sizes[0] / 5;              // 2048
    int words = (n + 63) / 64;            // 32
    int* keep = (int*)d_out;
    unsigned long long* mask = (unsigned long long*)d_ws;
    size_t mask_bytes = (size_t)n * words * sizeof(unsigned long long);

    hipMemsetAsync(mask, 0, mask_bytes, stream);
    hipMemsetAsync(d_out, 0xFF, (size_t)out_size * sizeof(int), stream); // -1 fill

    dim3 grid((n + 255) / 256, n);
    iou_mask_kernel<<<grid, 256, 0, stream>>>(boxes, mask, n, words);
    greedy_kernel<<<1, 64, 0, stream>>>(mask, keep, n, words);
}